// Round 9
// baseline (2403.925 us; speedup 1.0000x reference)
//
#include <hip/hip_runtime.h>

#define NTHR 512
#define NB   8
#define NOSC 50
#define NPER 40
#define KTOT 2000
#define KPAD 2048
#define NSTEP 700
#define BATCH 4096
#define B1STR 36
#define HALF_PI 1.57079632679489662f
#define ACT_OFF ((size_t)NSTEP * BATCH * 4)

typedef _Float16 v8h __attribute__((ext_vector_type(8)));
typedef _Float16 h2_t __attribute__((ext_vector_type(2)));
typedef float v4f __attribute__((ext_vector_type(4)));

__device__ _Float16 g_w4[32 * KPAD];    // fc4_w in f16, zero-padded K 2000->2048

__device__ __forceinline__ float fdot2f(float a_bits, float b_bits, float acc) {
    h2_t a = __builtin_bit_cast(h2_t, a_bits);
    h2_t b = __builtin_bit_cast(h2_t, b_bits);
#if __has_builtin(__builtin_amdgcn_fdot2)
    return __builtin_amdgcn_fdot2(a, b, acc, false);
#else
    return fmaf((float)a[0], (float)b[0], fmaf((float)a[1], (float)b[1], acc));
#endif
}

__device__ __forceinline__ float dot4(float4 a, float4 b, float acc) {
    acc = fmaf(a.x, b.x, acc);
    acc = fmaf(a.y, b.y, acc);
    acc = fmaf(a.z, b.z, acc);
    acc = fmaf(a.w, b.w, acc);
    return acc;
}

__device__ __forceinline__ float pkrtz(float a, float b) {
    auto q = __builtin_amdgcn_cvt_pkrtz(a, b);
    return __builtin_bit_cast(float, q);
}

__global__ void prep_f16(const float* __restrict__ fc4_w) {
    int tid = blockIdx.x * blockDim.x + threadIdx.x;   // 65536 total
    int j = tid >> 11, k = tid & 2047;
    g_w4[j * KPAD + k] = (k < KTOT) ? (_Float16)fc4_w[j * KTOT + k] : (_Float16)0.f;
}

// r7 post-mortem: no spills exist (FETCH 11 MB = compulsory only; AGPR file
// absorbs the >64-reg live state). The limit is barrier serialization of a
// single 16-wave block/CU. This round: NB=8, 512-thread blocks, 512 blocks
// -> TWO independent barrier domains per CU that overlap each other's stalls.
//   - act: 8 slots, 32 KB; MFMA rows 8-15 duplicate rows 0-7 (broadcast reads,
//     outputs unread). part halves to 16 KB, R reduces 8 partials.
//   - dec -> LDS (8-way broadcast reads), wr (16 frags) stays per-lane.
//   - LDS/block ~62 KB -> 2 blocks/CU; 16 waves/CU as before.
// act layout: element (b,k): oct = k>>3, j = k&7, slot = (b ^ oct) & 7
//   f16 idx = oct*64 + slot*8 + j
// 2 barriers/step:
//   P1: MFMA(all) + deriv(t<400) + fc5/limb/store(s-1) on t>=504
//   P2: R(t<256); phaseA(s+1) on t<500
__global__ __launch_bounds__(NTHR)
__attribute__((amdgpu_waves_per_eu(4, 4)))
void net_main(const float* __restrict__ x,
              const float* __restrict__ fc1_w, const float* __restrict__ fc1_b,
              const float* __restrict__ fc2_w, const float* __restrict__ fc2_b,
              const float* __restrict__ fc3_w, const float* __restrict__ fc3_b,
              const float* __restrict__ fcd_w, const float* __restrict__ fcd_b,
              const float* __restrict__ enc,   const float* __restrict__ osc_bias,
              const float* __restrict__ dec,
              const float* __restrict__ fc4_b,
              const float* __restrict__ fc5_w, const float* __restrict__ fc5_b,
              float* __restrict__ out)
{
    __shared__ __align__(16) _Float16 act_sh[256 * 64];   // 32 KB, frag-major
    __shared__ __align__(16) float part[8 * 2 * 256];     // 16 KB, MFMA partials (swizzled)
    __shared__ __align__(16) float os_sh[NOSC * NB * 2];  // 3.2 KB [o][b*2+d]
    __shared__ __align__(16) _Float16 dec_sh[4096];       // 8 KB [(o*2+d)*40+p]
    __shared__ __align__(16) float b1s[NB * B1STR];
    __shared__ __align__(16) float dir[NB * 2];

    const int t    = threadIdx.x;
    const int lane = t & 63;
    const int wv   = t >> 6;            // 0..7
    const int b0   = blockIdx.x * NB;

    float* h  = (float*)act_sh;         // [NB][128] f32 temp (pre-loop only)
    float* h2 = (float*)act_sh + NB * 128;

    // ---------- stage dec to LDS (f16 RTN, same as before) ----------
    for (int i = t; i < 4000; i += NTHR) dec_sh[i] = (_Float16)dec[i];

    // ---------- precompute: fc1 ----------
    #pragma unroll
    for (int ii = 0; ii < 2; ++ii) {
        int task = t + ii * NTHR;       // 1024 tasks
        int b = task >> 7, i = task & 127;
        float x0 = x[(b0 + b) * 2 + 0];
        float x1 = x[(b0 + b) * 2 + 1];
        float v = fmaf(x0, fc1_w[2 * i], fmaf(x1, fc1_w[2 * i + 1], fc1_b[i]));
        h[b * 128 + i] = fmaxf(v, 0.f);
    }
    __syncthreads();
    // ---------- precompute: fc2 -> h2, fcd -> dir ----------
    #pragma unroll
    for (int ii = 0; ii < 2; ++ii) {
        int task = t + ii * NTHR;       // 1024 tasks
        int b = task >> 7, i = task & 127;
        float acc = fc2_b[i];
        #pragma unroll 4
        for (int k = 0; k < 128; k += 4)
            acc = dot4(*(const float4*)&fc2_w[i * 128 + k],
                       *(const float4*)&h[b * 128 + k], acc);
        h2[b * 128 + i] = fmaxf(acc, 0.f);
    }
    if (t < NB * 2) {
        int b = t >> 1, j = t & 1;
        float acc = fcd_b[j];
        #pragma unroll 4
        for (int k = 0; k < 128; k += 4)
            acc = dot4(*(const float4*)&fcd_w[j * 128 + k],
                       *(const float4*)&h[b * 128 + k], acc);
        dir[b * 2 + j] = acc;
    }
    __syncthreads();
    // ---------- precompute: fc3 -> os_sh ----------
    #pragma unroll
    for (int ii = 0; ii < 2; ++ii) {
        int task = t + ii * NTHR;
        if (task < NOSC * NB * 2) {     // 800 tasks
            int o = task >> 4, r = task & 15, b = r >> 1;
            int row = o * 2 + (r & 1);
            float acc = fc3_b[row];
            #pragma unroll 4
            for (int k = 0; k < 128; k += 4)
                acc = dot4(*(const float4*)&fc3_w[row * 128 + k],
                           *(const float4*)&h2[b * 128 + k], acc);
            os_sh[o * 16 + r] = acc;
        }
    }
    // ---------- enc/bias -> per-thread registers (oct fixed per thread) ----------
    const int my_oct = t >> 1;          // 0..255; octs >= 250 idle in phaseA
    float4 e0 = {0,0,0,0}, e1 = {0,0,0,0}, e2 = {0,0,0,0}, e3 = {0,0,0,0};
    float4 bi0 = {0,0,0,0}, bi1 = {0,0,0,0};
    int my_o = 0;
    if (my_oct < 250) {
        const float4* ep = (const float4*)&enc[my_oct * 16];
        e0 = ep[0]; e1 = ep[1]; e2 = ep[2]; e3 = ep[3];
        const float4* bp = (const float4*)&osc_bias[my_oct * 8];
        bi0 = bp[0]; bi1 = bp[1];
        my_o = my_oct / 5;
    }
    // ---------- limb init (threads 504..511 own the ODE + stores) ----------
    float theta = 0.f, omega = 0.f, l1 = 0.f, l2 = 0.f, bs0 = 0.f, bs1 = 0.f;
    const int cb = t - 504;             // 0..7 on tail of wave 7
    if (cb >= 0 && cb < NB) {
        theta = x[(b0 + cb) * 2 + 0];
        l1 = fmaf(-0.02f, theta, 0.1f);
        l2 = fmaf( 0.02f, theta, 0.1f);
    }
    __syncthreads();
    if (cb >= 0 && cb < NB) {
        bs0 = dir[cb * 2 + 0] + fc5_b[0];
        bs1 = dir[cb * 2 + 1] + fc5_b[1];
    }
    // zero act padding (octs 250..255 -> f16 idx [16000, 16384))
    if (t < 384) act_sh[16000 + t] = (_Float16)0.f;

    // ---------- loop-invariant MFMA indices + weights in regs/AGPRs ----------
    const int n_col = lane & 15, quad = lane >> 4;
    const int nc8   = n_col & 7;                    // batch row (dup 8-15)
    const int lidx  = lane ^ (quad << 2);           // part write swizzle
    int a_off[8];
    #pragma unroll
    for (int ks = 0; ks < 8; ++ks) {
        int oct = (wv * 8 + ks) * 4 + quad;
        a_off[ks] = oct * 64 + ((nc8 ^ (oct & 7)) * 8);
    }
    v8h wr[16];                         // B-fragments for all 16 MFMAs
    {
        const _Float16* wp = &g_w4[n_col * KPAD + wv * 256 + quad * 8];
        #pragma unroll
        for (int ks = 0; ks < 8; ++ks) {
            wr[ks]     = *(const v8h*)&wp[ks * 32];
            wr[8 + ks] = *(const v8h*)&wp[16 * KPAD + ks * 32];
        }
    }

    // ---------- phase A: act = relu(enc . os + bias), enc/bias in regs ----------
    // thread (my_oct = t>>1) covers b = (t&1)*4 + ii, ii=0..3
    auto phaseA = [&]() {
        if (my_oct < 250) {
            const int i4 = (t & 1) << 2;
            float4 osA = *(const float4*)&os_sh[my_o * 16 + i4 * 2];      // b=i4+0,1
            float4 osB = *(const float4*)&os_sh[my_o * 16 + i4 * 2 + 4];  // b=i4+2,3
            #pragma unroll
            for (int ii = 0; ii < 4; ++ii) {
                int b = i4 + ii;
                float osx = (ii == 0) ? osA.x : (ii == 1) ? osA.z : (ii == 2) ? osB.x : osB.z;
                float osy = (ii == 0) ? osA.y : (ii == 1) ? osA.w : (ii == 2) ? osB.y : osB.w;
                float r0 = fmaxf(fmaf(e0.x, osx, fmaf(e0.y, osy, bi0.x)), 0.f);
                float r1 = fmaxf(fmaf(e0.z, osx, fmaf(e0.w, osy, bi0.y)), 0.f);
                float r2 = fmaxf(fmaf(e1.x, osx, fmaf(e1.y, osy, bi0.z)), 0.f);
                float r3 = fmaxf(fmaf(e1.z, osx, fmaf(e1.w, osy, bi0.w)), 0.f);
                float r4 = fmaxf(fmaf(e2.x, osx, fmaf(e2.y, osy, bi1.x)), 0.f);
                float r5 = fmaxf(fmaf(e2.z, osx, fmaf(e2.w, osy, bi1.y)), 0.f);
                float r6 = fmaxf(fmaf(e3.x, osx, fmaf(e3.y, osy, bi1.z)), 0.f);
                float r7 = fmaxf(fmaf(e3.z, osx, fmaf(e3.w, osy, bi1.w)), 0.f);
                float4 pk;
                pk.x = pkrtz(r0, r1);
                pk.y = pkrtz(r2, r3);
                pk.z = pkrtz(r4, r5);
                pk.w = pkrtz(r6, r7);
                *(float4*)&act_sh[my_oct * 64 + ((b ^ my_oct) & 7) * 8] = pk;
            }
        }
    };

    phaseA();                   // act(0)
    __syncthreads();

    for (int s = 0; s < NSTEP; ++s) {
        // ---- P1: MFMA (all) + deriv (t<400) + t>=504: fc5/limb/store(s-1) ----
        {
            v4f c0 = {0.f, 0.f, 0.f, 0.f}, c1 = {0.f, 0.f, 0.f, 0.f};
            #pragma unroll
            for (int ks = 0; ks < 8; ++ks) {
                v8h a = *(const v8h*)&act_sh[a_off[ks]];
                c0 = __builtin_amdgcn_mfma_f32_16x16x32_f16(a, wr[ks],     c0, 0, 0, 0);
                c1 = __builtin_amdgcn_mfma_f32_16x16x32_f16(a, wr[8 + ks], c1, 0, 0, 0);
            }
            *(v4f*)&part[(wv * 2 + 0) * 256 + lidx * 4] = c0;
            *(v4f*)&part[(wv * 2 + 1) * 256 + lidx * 4] = c1;
        }
        if (t < NOSC * NB) {            // deriv: (o,b) task, dec via LDS broadcast
            int o = t >> 3, b = t & 7;
            const _Float16* dr0 = &dec_sh[(o * 2 + 0) * 40];
            const _Float16* dr1 = &dec_sh[(o * 2 + 1) * 40];
            float p0 = 0.f, p1 = 0.f, q0 = 0.f, q1 = 0.f;
            #pragma unroll
            for (int c = 0; c < 5; ++c) {
                int oct = o * 5 + c;
                float4 af = *(const float4*)&act_sh[oct * 64 + ((b ^ oct) & 7) * 8];
                float4 d0 = *(const float4*)&dr0[c * 8];
                float4 d1 = *(const float4*)&dr1[c * 8];
                p0 = fdot2f(af.x, d0.x, p0); p1 = fdot2f(af.y, d0.y, p1);
                p0 = fdot2f(af.z, d0.z, p0); p1 = fdot2f(af.w, d0.w, p1);
                q0 = fdot2f(af.x, d1.x, q0); q1 = fdot2f(af.y, d1.y, q1);
                q0 = fdot2f(af.z, d1.z, q0); q1 = fdot2f(af.w, d1.w, q1);
            }
            float2 osv = *(const float2*)&os_sh[o * 16 + b * 2];
            osv.x += 0.001f * (p0 + p1);
            osv.y += 0.001f * (q0 + q1);
            *(float2*)&os_sh[o * 16 + b * 2] = osv;
        } else if (cb >= 0 && cb < NB && s > 0) {
            // fc5 + limb ODE + stores for step s-1 (b1s from P2 of s-1)
            float a0 = bs0, a1 = bs1;
            #pragma unroll
            for (int i = 0; i < 32; i += 4) {
                float4 bv = *(const float4*)&b1s[cb * B1STR + i];
                a0 = dot4(bv, *(const float4*)&fc5_w[i],      a0);
                a1 = dot4(bv, *(const float4*)&fc5_w[32 + i], a1);
            }
            float f1v = fmaxf(a0, 0.f) * 50.f * fmaxf(l1 - 0.05f, 0.f);
            float f2v = fmaxf(a1, 0.f) * 50.f * fmaxf(l2 - 0.05f, 0.f);
            float domega = (0.02f * (f2v - f1v) - 0.01f * omega) / 0.001f;
            float dl1 = ((0.1f - 0.02f * theta) - l1) / 0.05f;
            float dl2 = ((0.1f + 0.02f * theta) - l2) / 0.05f;
            float pos = fmaf(0.001f, omega,  theta);
            float vel = fmaf(0.001f, domega, omega);
            l1 = fmaf(0.001f, dl1, l1);
            l2 = fmaf(0.001f, dl2, l2);
            bool inb = (pos > -HALF_PI) && (pos < HALF_PI);
            float posc = fminf(fmaxf(pos, -HALF_PI), HALF_PI);
            vel = inb ? vel : 0.f;
            theta = posc;
            omega = vel;
            float4 lo; lo.x = posc; lo.y = vel; lo.z = l1; lo.w = l2;
            *(float4*)&out[((size_t)(s - 1) * BATCH + (b0 + cb)) * 4] = lo;
            float2 ao; ao.x = a0; ao.y = a1;
            *(float2*)&out[ACT_OFF + ((size_t)(s - 1) * BATCH + (b0 + cb)) * 2] = ao;
        }
        __syncthreads();

        // ---- P2: t<256: R -> b1s; t<500: phaseA(s+1) ----
        if (t < 256) {
            int b = t & 7, j = t >> 3;          // b 0..7, j 0..31
            int g = j >> 4, n = j & 15;
            int q = b >> 2;                     // 0..1 (rows 0..7 only)
            int Lp = q * 16 + (n ^ (q << 2));   // un-swizzle
            int base = g * 256 + Lp * 4 + (b & 3);
            float sum = 0.f;
            #pragma unroll
            for (int w = 0; w < 8; ++w)
                sum += part[w * 512 + base];
            b1s[b * B1STR + j] = fmaxf(sum + fc4_b[j], 0.f);
        }
        phaseA();
        __syncthreads();
    }

    // ---- tail: fc5 + limb + store for the final step ----
    if (cb >= 0 && cb < NB) {
        const int s = NSTEP - 1;
        float a0 = bs0, a1 = bs1;
        #pragma unroll
        for (int i = 0; i < 32; i += 4) {
            float4 bv = *(const float4*)&b1s[cb * B1STR + i];
            a0 = dot4(bv, *(const float4*)&fc5_w[i],      a0);
            a1 = dot4(bv, *(const float4*)&fc5_w[32 + i], a1);
        }
        float f1v = fmaxf(a0, 0.f) * 50.f * fmaxf(l1 - 0.05f, 0.f);
        float f2v = fmaxf(a1, 0.f) * 50.f * fmaxf(l2 - 0.05f, 0.f);
        float domega = (0.02f * (f2v - f1v) - 0.01f * omega) / 0.001f;
        float dl1 = ((0.1f - 0.02f * theta) - l1) / 0.05f;
        float dl2 = ((0.1f + 0.02f * theta) - l2) / 0.05f;
        float pos = fmaf(0.001f, omega,  theta);
        float vel = fmaf(0.001f, domega, omega);
        l1 = fmaf(0.001f, dl1, l1);
        l2 = fmaf(0.001f, dl2, l2);
        bool inb = (pos > -HALF_PI) && (pos < HALF_PI);
        float posc = fminf(fmaxf(pos, -HALF_PI), HALF_PI);
        vel = inb ? vel : 0.f;
        float4 lo; lo.x = posc; lo.y = vel; lo.z = l1; lo.w = l2;
        *(float4*)&out[((size_t)s * BATCH + (b0 + cb)) * 4] = lo;
        float2 ao; ao.x = a0; ao.y = a1;
        *(float2*)&out[ACT_OFF + ((size_t)s * BATCH + (b0 + cb)) * 2] = ao;
    }
}

extern "C" void kernel_launch(void* const* d_in, const int* in_sizes, int n_in,
                              void* d_out, int out_size, void* d_ws, size_t ws_size,
                              hipStream_t stream) {
    (void)in_sizes; (void)n_in; (void)d_ws; (void)ws_size; (void)out_size;
    const float* x_     = (const float*)d_in[0];
    const float* fc1_w  = (const float*)d_in[1];
    const float* fc1_b  = (const float*)d_in[2];
    const float* fc2_w  = (const float*)d_in[3];
    const float* fc2_b  = (const float*)d_in[4];
    const float* fc3_w  = (const float*)d_in[5];
    const float* fc3_b  = (const float*)d_in[6];
    const float* fcd_w  = (const float*)d_in[7];
    const float* fcd_b  = (const float*)d_in[8];
    const float* enc    = (const float*)d_in[9];
    const float* oscb   = (const float*)d_in[10];
    const float* dec    = (const float*)d_in[11];
    const float* fc4_w  = (const float*)d_in[12];
    const float* fc4_b  = (const float*)d_in[13];
    const float* fc5_w  = (const float*)d_in[14];
    const float* fc5_b  = (const float*)d_in[15];
    float* out = (float*)d_out;

    hipLaunchKernelGGL(prep_f16, dim3(256), dim3(256), 0, stream, fc4_w);
    hipLaunchKernelGGL(net_main, dim3(BATCH / NB), dim3(NTHR), 0, stream,
                       x_, fc1_w, fc1_b, fc2_w, fc2_b, fc3_w, fc3_b,
                       fcd_w, fcd_b, enc, oscb, dec, fc4_b,
                       fc5_w, fc5_b, out);
}

// Round 10
// 2005.422 us; speedup vs baseline: 1.1987x; 1.1987x over previous
//
#include <hip/hip_runtime.h>

#define NTHR 1024
#define NB   16
#define NOSC 50
#define NPER 40
#define KTOT 2000
#define KPAD 2048
#define NSTEP 700
#define BATCH 4096
#define B1STR 36
#define OS_STR 36
#define HALF_PI 1.57079632679489662f
#define ACT_OFF ((size_t)NSTEP * BATCH * 4)

typedef _Float16 v8h __attribute__((ext_vector_type(8)));
typedef _Float16 h2_t __attribute__((ext_vector_type(2)));
typedef float v4f __attribute__((ext_vector_type(4)));

__device__ _Float16 g_w4[32 * KPAD];    // fc4_w in f16, zero-padded K 2000->2048

__device__ __forceinline__ float fdot2f(float a_bits, float b_bits, float acc) {
    h2_t a = __builtin_bit_cast(h2_t, a_bits);
    h2_t b = __builtin_bit_cast(h2_t, b_bits);
#if __has_builtin(__builtin_amdgcn_fdot2)
    return __builtin_amdgcn_fdot2(a, b, acc, false);
#else
    return fmaf((float)a[0], (float)b[0], fmaf((float)a[1], (float)b[1], acc));
#endif
}

__device__ __forceinline__ float dot4(float4 a, float4 b, float acc) {
    acc = fmaf(a.x, b.x, acc);
    acc = fmaf(a.y, b.y, acc);
    acc = fmaf(a.z, b.z, acc);
    acc = fmaf(a.w, b.w, acc);
    return acc;
}

__device__ __forceinline__ float pkrtz(float a, float b) {
    auto q = __builtin_amdgcn_cvt_pkrtz(a, b);
    return __builtin_bit_cast(float, q);
}

// pack 2 f32 -> 2 f16 with round-to-nearest (matches old (_Float16) LDS staging)
__device__ __forceinline__ float cvt2rtn(float a, float b) {
    h2_t u; u[0] = (_Float16)a; u[1] = (_Float16)b;
    return __builtin_bit_cast(float, u);
}

__global__ void prep_f16(const float* __restrict__ fc4_w) {
    int tid = blockIdx.x * blockDim.x + threadIdx.x;   // 65536 total
    int j = tid >> 11, k = tid & 2047;
    g_w4[j * KPAD + k] = (k < KTOT) ? (_Float16)fc4_w[j * KTOT + k] : (_Float16)0.f;
}

// act layout: element (b, k): oct = k>>3, j = k&7, slot = (b ^ oct) & 15
//   f16 idx = oct*128 + slot*8 + j
// r9 post-mortem: NB=8 regressed (MFMA M=16 makes half the tile waste) but
// ISOLATED the conflict source: os_sh o-stride 32 words == 0 mod 32 banks ->
// all lanes with equal t&3 / equal b collapse onto one 4-bank group in
// phaseA / deriv os accesses (~1300 conflict cyc/CU-step, 18% of step).
// Fix: OS_STR=36 (o advances 4 banks; 144 B keeps float4 alignment).
// Structure = r6 best (2042 us): NB=16, 16 waves, weights in regs/AGPRs,
// 2 barriers/step:
//   P1: MFMA(all) + deriv(t<800) + wave15: fc5/limb/store of step s-1
//   P2: waves0-7: R -> b1s; all: phaseA(s+1)
__global__ __launch_bounds__(NTHR)
void net_main(const float* __restrict__ x,
              const float* __restrict__ fc1_w, const float* __restrict__ fc1_b,
              const float* __restrict__ fc2_w, const float* __restrict__ fc2_b,
              const float* __restrict__ fc3_w, const float* __restrict__ fc3_b,
              const float* __restrict__ fcd_w, const float* __restrict__ fcd_b,
              const float* __restrict__ enc,   const float* __restrict__ osc_bias,
              const float* __restrict__ dec,
              const float* __restrict__ fc4_b,
              const float* __restrict__ fc5_w, const float* __restrict__ fc5_b,
              float* __restrict__ out)
{
    __shared__ __align__(16) _Float16 act_sh[256 * 128];  // 64 KB, frag-major
    __shared__ __align__(16) float part[16 * 2 * 256];    // 32 KB, MFMA partials (swizzled)
    __shared__ __align__(16) float os_sh[NOSC * OS_STR];  // 7.2 KB [o][b*2+d], padded stride
    __shared__ __align__(16) float b1s[NB * B1STR];
    __shared__ __align__(16) float dir[NB * 2];

    const int t    = threadIdx.x;
    const int lane = t & 63;
    const int wv   = t >> 6;            // 0..15
    const int b0   = blockIdx.x * NB;

    float* h  = (float*)act_sh;         // [NB][128] f32 temp (pre-loop only)
    float* h2 = (float*)act_sh + NB * 128;

    // ---------- precompute: fc1 ----------
    #pragma unroll
    for (int ii = 0; ii < 2; ++ii) {
        int task = t + ii * NTHR;       // 2048 tasks
        int b = task >> 7, i = task & 127;
        float x0 = x[(b0 + b) * 2 + 0];
        float x1 = x[(b0 + b) * 2 + 1];
        float v = fmaf(x0, fc1_w[2 * i], fmaf(x1, fc1_w[2 * i + 1], fc1_b[i]));
        h[b * 128 + i] = fmaxf(v, 0.f);
    }
    __syncthreads();
    // ---------- precompute: fc2 -> h2, fcd -> dir ----------
    #pragma unroll
    for (int ii = 0; ii < 2; ++ii) {
        int task = t + ii * NTHR;
        int b = task >> 7, i = task & 127;
        float acc = fc2_b[i];
        #pragma unroll 4
        for (int k = 0; k < 128; k += 4)
            acc = dot4(*(const float4*)&fc2_w[i * 128 + k],
                       *(const float4*)&h[b * 128 + k], acc);
        h2[b * 128 + i] = fmaxf(acc, 0.f);
    }
    if (t < NB * 2) {
        int b = t >> 1, j = t & 1;
        float acc = fcd_b[j];
        #pragma unroll 4
        for (int k = 0; k < 128; k += 4)
            acc = dot4(*(const float4*)&fcd_w[j * 128 + k],
                       *(const float4*)&h[b * 128 + k], acc);
        dir[b * 2 + j] = acc;
    }
    __syncthreads();
    // ---------- precompute: fc3 -> os_sh ----------
    #pragma unroll
    for (int ii = 0; ii < 2; ++ii) {
        int task = t + ii * NTHR;
        if (task < NOSC * NB * 2) {     // 1600 tasks
            int o = task >> 5, r = task & 31, b = r >> 1;
            int row = o * 2 + (r & 1);
            float acc = fc3_b[row];
            #pragma unroll 4
            for (int k = 0; k < 128; k += 4)
                acc = dot4(*(const float4*)&fc3_w[row * 128 + k],
                           *(const float4*)&h2[b * 128 + k], acc);
            os_sh[o * OS_STR + r] = acc;
        }
    }
    // ---------- enc/bias -> per-thread registers (oct fixed per thread) ----------
    const int my_oct = t >> 2;          // 0..255; threads with oct>=250 idle in phaseA
    float4 e0 = {0,0,0,0}, e1 = {0,0,0,0}, e2 = {0,0,0,0}, e3 = {0,0,0,0};
    float4 bi0 = {0,0,0,0}, bi1 = {0,0,0,0};
    int my_o = 0;
    if (my_oct < 250) {
        const float4* ep = (const float4*)&enc[my_oct * 16];
        e0 = ep[0]; e1 = ep[1]; e2 = ep[2]; e3 = ep[3];
        const float4* bp = (const float4*)&osc_bias[my_oct * 8];
        bi0 = bp[0]; bi1 = bp[1];
        my_o = my_oct / 5;
    }
    // ---------- dec -> per-thread registers (deriv task (o,b) per thread) ----------
    float4 dd0[5], dd1[5];
    if (t < NOSC * NB) {                // 800 threads
        int o = t >> 4;
        const float* d0p = &dec[(o * 2 + 0) * 40];
        const float* d1p = &dec[(o * 2 + 1) * 40];
        #pragma unroll
        for (int c = 0; c < 5; ++c) {
            dd0[c].x = cvt2rtn(d0p[c*8+0], d0p[c*8+1]);
            dd0[c].y = cvt2rtn(d0p[c*8+2], d0p[c*8+3]);
            dd0[c].z = cvt2rtn(d0p[c*8+4], d0p[c*8+5]);
            dd0[c].w = cvt2rtn(d0p[c*8+6], d0p[c*8+7]);
            dd1[c].x = cvt2rtn(d1p[c*8+0], d1p[c*8+1]);
            dd1[c].y = cvt2rtn(d1p[c*8+2], d1p[c*8+3]);
            dd1[c].z = cvt2rtn(d1p[c*8+4], d1p[c*8+5]);
            dd1[c].w = cvt2rtn(d1p[c*8+6], d1p[c*8+7]);
        }
    }
    // ---------- limb init (wave 15 owns the ODE + stores) ----------
    float theta = 0.f, omega = 0.f, l1 = 0.f, l2 = 0.f, bs0 = 0.f, bs1 = 0.f;
    const int cb = t - 960;             // 0..15 on wave 15
    if (cb >= 0 && cb < NB) {
        theta = x[(b0 + cb) * 2 + 0];
        l1 = fmaf(-0.02f, theta, 0.1f);
        l2 = fmaf( 0.02f, theta, 0.1f);
    }
    __syncthreads();
    if (cb >= 0 && cb < NB) {
        bs0 = dir[cb * 2 + 0] + fc5_b[0];
        bs1 = dir[cb * 2 + 1] + fc5_b[1];
    }
    // zero act padding (octets 250..255 -> f16 idx [32000, 32768))
    if (t < 768) act_sh[32000 + t] = (_Float16)0.f;

    // ---------- loop-invariant MFMA indices + WEIGHTS IN REGISTERS ----------
    const int n_col = lane & 15, quad = lane >> 4;
    const int lidx  = lane ^ (quad << 2);           // part write swizzle
    int a_off[4];
    #pragma unroll
    for (int ks4 = 0; ks4 < 4; ++ks4) {
        int oct = (wv * 4 + ks4) * 4 + quad;
        a_off[ks4] = oct * 128 + ((n_col ^ (oct & 15)) * 8);
    }
    v8h wr[8];                          // 32 VGPR: B-fragments for all 8 MFMAs
    {
        const _Float16* wp = &g_w4[n_col * KPAD + wv * 128 + quad * 8];
        #pragma unroll
        for (int ks4 = 0; ks4 < 4; ++ks4) {
            wr[ks4]     = *(const v8h*)&wp[ks4 * 32];
            wr[4 + ks4] = *(const v8h*)&wp[16 * KPAD + ks4 * 32];
        }
    }

    // ---------- phase A: act = relu(enc . os + bias), enc/bias in REGISTERS ----------
    // thread covers b = (t&3)*4 + ii, ii=0..3 -> slot bijective per 16-lane group
    auto phaseA = [&]() {
        if (my_oct < 250) {
            const int i4 = (t & 3) << 2;
            float4 osA = *(const float4*)&os_sh[my_o * OS_STR + i4 * 2];      // b=i4+0,1
            float4 osB = *(const float4*)&os_sh[my_o * OS_STR + i4 * 2 + 4];  // b=i4+2,3
            #pragma unroll
            for (int ii = 0; ii < 4; ++ii) {
                int b = i4 + ii;
                float osx = (ii == 0) ? osA.x : (ii == 1) ? osA.z : (ii == 2) ? osB.x : osB.z;
                float osy = (ii == 0) ? osA.y : (ii == 1) ? osA.w : (ii == 2) ? osB.y : osB.w;
                float r0 = fmaxf(fmaf(e0.x, osx, fmaf(e0.y, osy, bi0.x)), 0.f);
                float r1 = fmaxf(fmaf(e0.z, osx, fmaf(e0.w, osy, bi0.y)), 0.f);
                float r2 = fmaxf(fmaf(e1.x, osx, fmaf(e1.y, osy, bi0.z)), 0.f);
                float r3 = fmaxf(fmaf(e1.z, osx, fmaf(e1.w, osy, bi0.w)), 0.f);
                float r4 = fmaxf(fmaf(e2.x, osx, fmaf(e2.y, osy, bi1.x)), 0.f);
                float r5 = fmaxf(fmaf(e2.z, osx, fmaf(e2.w, osy, bi1.y)), 0.f);
                float r6 = fmaxf(fmaf(e3.x, osx, fmaf(e3.y, osy, bi1.z)), 0.f);
                float r7 = fmaxf(fmaf(e3.z, osx, fmaf(e3.w, osy, bi1.w)), 0.f);
                float4 pk;
                pk.x = pkrtz(r0, r1);
                pk.y = pkrtz(r2, r3);
                pk.z = pkrtz(r4, r5);
                pk.w = pkrtz(r6, r7);
                *(float4*)&act_sh[my_oct * 128 + ((b ^ my_oct) & 15) * 8] = pk;
            }
        }
    };

    phaseA();                   // act(0)
    __syncthreads();

    for (int s = 0; s < NSTEP; ++s) {
        // ---- P1: MFMA (all) + deriv (t<800) + wave15: fc5/limb/store(s-1) ----
        {
            v4f c0 = {0.f, 0.f, 0.f, 0.f}, c1 = {0.f, 0.f, 0.f, 0.f};
            #pragma unroll
            for (int ks4 = 0; ks4 < 4; ++ks4) {
                v8h a = *(const v8h*)&act_sh[a_off[ks4]];
                c0 = __builtin_amdgcn_mfma_f32_16x16x32_f16(a, wr[ks4],     c0, 0, 0, 0);
                c1 = __builtin_amdgcn_mfma_f32_16x16x32_f16(a, wr[4 + ks4], c1, 0, 0, 0);
            }
            *(v4f*)&part[(wv * 2 + 0) * 256 + lidx * 4] = c0;
            *(v4f*)&part[(wv * 2 + 1) * 256 + lidx * 4] = c1;
        }
        if (t < NOSC * NB) {            // deriv: one (o,b) task, both d, dec in regs
            int o = t >> 4, b = t & 15;
            float p0 = 0.f, p1 = 0.f, q0 = 0.f, q1 = 0.f;
            #pragma unroll
            for (int c = 0; c < 5; ++c) {
                int oct = o * 5 + c;
                float4 af = *(const float4*)&act_sh[oct * 128 + ((b ^ oct) & 15) * 8];
                p0 = fdot2f(af.x, dd0[c].x, p0); p1 = fdot2f(af.y, dd0[c].y, p1);
                p0 = fdot2f(af.z, dd0[c].z, p0); p1 = fdot2f(af.w, dd0[c].w, p1);
                q0 = fdot2f(af.x, dd1[c].x, q0); q1 = fdot2f(af.y, dd1[c].y, q1);
                q0 = fdot2f(af.z, dd1[c].z, q0); q1 = fdot2f(af.w, dd1[c].w, q1);
            }
            float2 osv = *(const float2*)&os_sh[o * OS_STR + b * 2];
            osv.x += 0.001f * (p0 + p1);
            osv.y += 0.001f * (q0 + q1);
            *(float2*)&os_sh[o * OS_STR + b * 2] = osv;
        } else if (cb >= 0 && cb < NB && s > 0) {
            // fc5 + limb ODE + stores for step s-1 (b1s from P2 of s-1)
            float a0 = bs0, a1 = bs1;
            #pragma unroll
            for (int i = 0; i < 32; i += 4) {
                float4 bv = *(const float4*)&b1s[cb * B1STR + i];
                a0 = dot4(bv, *(const float4*)&fc5_w[i],      a0);
                a1 = dot4(bv, *(const float4*)&fc5_w[32 + i], a1);
            }
            float f1v = fmaxf(a0, 0.f) * 50.f * fmaxf(l1 - 0.05f, 0.f);
            float f2v = fmaxf(a1, 0.f) * 50.f * fmaxf(l2 - 0.05f, 0.f);
            float domega = (0.02f * (f2v - f1v) - 0.01f * omega) / 0.001f;
            float dl1 = ((0.1f - 0.02f * theta) - l1) / 0.05f;
            float dl2 = ((0.1f + 0.02f * theta) - l2) / 0.05f;
            float pos = fmaf(0.001f, omega,  theta);
            float vel = fmaf(0.001f, domega, omega);
            l1 = fmaf(0.001f, dl1, l1);
            l2 = fmaf(0.001f, dl2, l2);
            bool inb = (pos > -HALF_PI) && (pos < HALF_PI);
            float posc = fminf(fmaxf(pos, -HALF_PI), HALF_PI);
            vel = inb ? vel : 0.f;
            theta = posc;
            omega = vel;
            float4 lo; lo.x = posc; lo.y = vel; lo.z = l1; lo.w = l2;
            *(float4*)&out[((size_t)(s - 1) * BATCH + (b0 + cb)) * 4] = lo;
            float2 ao; ao.x = a0; ao.y = a1;
            *(float2*)&out[ACT_OFF + ((size_t)(s - 1) * BATCH + (b0 + cb)) * 2] = ao;
        }
        __syncthreads();

        // ---- P2: waves0-7: R -> b1s; all: phaseA(s+1) ----
        if (t < 512) {
            int b = t & 15, j = t >> 4;         // b 0..15, j 0..31
            int g = j >> 4, n = j & 15;
            int Lp = (b >> 2) * 16 + (n ^ ((b >> 2) << 2));   // un-swizzle
            int base = g * 256 + Lp * 4 + (b & 3);
            float sum = 0.f;
            #pragma unroll
            for (int w = 0; w < 16; ++w)
                sum += part[w * 512 + base];
            b1s[b * B1STR + j] = fmaxf(sum + fc4_b[j], 0.f);
        }
        phaseA();
        __syncthreads();
    }

    // ---- tail: fc5 + limb + store for the final step ----
    if (cb >= 0 && cb < NB) {
        const int s = NSTEP - 1;
        float a0 = bs0, a1 = bs1;
        #pragma unroll
        for (int i = 0; i < 32; i += 4) {
            float4 bv = *(const float4*)&b1s[cb * B1STR + i];
            a0 = dot4(bv, *(const float4*)&fc5_w[i],      a0);
            a1 = dot4(bv, *(const float4*)&fc5_w[32 + i], a1);
        }
        float f1v = fmaxf(a0, 0.f) * 50.f * fmaxf(l1 - 0.05f, 0.f);
        float f2v = fmaxf(a1, 0.f) * 50.f * fmaxf(l2 - 0.05f, 0.f);
        float domega = (0.02f * (f2v - f1v) - 0.01f * omega) / 0.001f;
        float dl1 = ((0.1f - 0.02f * theta) - l1) / 0.05f;
        float dl2 = ((0.1f + 0.02f * theta) - l2) / 0.05f;
        float pos = fmaf(0.001f, omega,  theta);
        float vel = fmaf(0.001f, domega, omega);
        l1 = fmaf(0.001f, dl1, l1);
        l2 = fmaf(0.001f, dl2, l2);
        bool inb = (pos > -HALF_PI) && (pos < HALF_PI);
        float posc = fminf(fmaxf(pos, -HALF_PI), HALF_PI);
        vel = inb ? vel : 0.f;
        float4 lo; lo.x = posc; lo.y = vel; lo.z = l1; lo.w = l2;
        *(float4*)&out[((size_t)s * BATCH + (b0 + cb)) * 4] = lo;
        float2 ao; ao.x = a0; ao.y = a1;
        *(float2*)&out[ACT_OFF + ((size_t)s * BATCH + (b0 + cb)) * 2] = ao;
    }
}

extern "C" void kernel_launch(void* const* d_in, const int* in_sizes, int n_in,
                              void* d_out, int out_size, void* d_ws, size_t ws_size,
                              hipStream_t stream) {
    (void)in_sizes; (void)n_in; (void)d_ws; (void)ws_size; (void)out_size;
    const float* x_     = (const float*)d_in[0];
    const float* fc1_w  = (const float*)d_in[1];
    const float* fc1_b  = (const float*)d_in[2];
    const float* fc2_w  = (const float*)d_in[3];
    const float* fc2_b  = (const float*)d_in[4];
    const float* fc3_w  = (const float*)d_in[5];
    const float* fc3_b  = (const float*)d_in[6];
    const float* fcd_w  = (const float*)d_in[7];
    const float* fcd_b  = (const float*)d_in[8];
    const float* enc    = (const float*)d_in[9];
    const float* oscb   = (const float*)d_in[10];
    const float* dec    = (const float*)d_in[11];
    const float* fc4_w  = (const float*)d_in[12];
    const float* fc4_b  = (const float*)d_in[13];
    const float* fc5_w  = (const float*)d_in[14];
    const float* fc5_b  = (const float*)d_in[15];
    float* out = (float*)d_out;

    hipLaunchKernelGGL(prep_f16, dim3(256), dim3(256), 0, stream, fc4_w);
    hipLaunchKernelGGL(net_main, dim3(BATCH / NB), dim3(NTHR), 0, stream,
                       x_, fc1_w, fc1_b, fc2_w, fc2_b, fc3_w, fc3_b,
                       fcd_w, fcd_b, enc, oscb, dec, fc4_b,
                       fc5_w, fc5_b, out);
}